// Round 8
// baseline (139.243 us; speedup 1.0000x reference)
//
#include <hip/hip_runtime.h>
#include <cstdint>
#include <cstddef>

typedef _Float16 f16;
typedef f16 f16x8 __attribute__((ext_vector_type(8)));
typedef f16 f16x4 __attribute__((ext_vector_type(4)));
typedef float f32x4 __attribute__((ext_vector_type(4)));

constexpr int NS = 2048;     // sites
constexpr int NB = 65536;    // bonds
// d_in order: sites, bonds, states, indices1, W1, b1, W2, b2, W3, b3 (all f32, idx int32)

// ---------------- pack (blocks 0..63) + count (blocks 64..319) ----------------
__global__ void pack_count_kernel(const float* __restrict__ W1, const float* __restrict__ W2,
                                  const float* __restrict__ W3, f16* __restrict__ pw1,
                                  f16* __restrict__ pw2, f16* __restrict__ pw3,
                                  const int* __restrict__ idx, int* __restrict__ counts) {
    if (blockIdx.x < 64) {
        int t = blockIdx.x * 256 + threadIdx.x;   // 16384 threads
        int tt = t >> 6, l = t & 63;
        const float* W; f16* dst; int N, tloc, kt, nt;
        if (tt < 96)       { W = W1; dst = pw1; N = 256; tloc = tt;       kt = tloc >> 4; nt = tloc & 15; }
        else if (tt < 224) { W = W2; dst = pw2; N = 256; tloc = tt - 96;  kt = tloc >> 4; nt = tloc & 15; }
        else               { W = W3; dst = pw3; N = 64;  tloc = tt - 224; kt = tloc >> 2; nt = tloc & 3;  }
        int kbase = kt * 32 + (l >> 4) * 8;
        int n = nt * 16 + (l & 15);
        f16x8 o;
        #pragma unroll
        for (int j = 0; j < 8; ++j) o[j] = (f16)W[(size_t)(kbase + j) * N + n];
        *reinterpret_cast<f16x8*>(&dst[(size_t)(tloc * 64 + l) * 8]) = o;
    } else {
        int i = (blockIdx.x - 64) * 256 + threadIdx.x;   // 65536 threads
        atomicAdd(&counts[idx[i]], 1);
    }
}

__global__ void scan_kernel(const int* __restrict__ counts, int* __restrict__ offsets) {
    int l = threadIdx.x;            // 64 lanes, each owns 32 contiguous sites
    int c[32]; int run = 0;
    #pragma unroll
    for (int i = 0; i < 32; ++i) { c[i] = run; run += counts[l * 32 + i]; }
    int incl = run;
    #pragma unroll
    for (int d = 1; d < 64; d <<= 1) { int v = __shfl_up(incl, d); if (l >= d) incl += v; }
    int excl = incl - run;
    #pragma unroll
    for (int i = 0; i < 32; ++i) offsets[l * 32 + i] = excl + c[i];
}

// ---------------- conv: linear-stream bonds f32 -> CSR-sorted f16 copy ----------------
// block = 64 consecutive bond rows, all 16 batches. Reads are fully coalesced
// (wave = 8 rows x 256B contiguous); writes are 128B cacheline-aligned rows at
// the CSR-sorted position (rank via atomicAdd cursor; within-segment order only
// permutes an f32 summation). Turns the 2 TB/s random-gather into linear traffic.
__global__ __launch_bounds__(256) void conv_kernel(
    const float* __restrict__ bonds, const int* __restrict__ idx,
    const int* __restrict__ offsets, int* __restrict__ cursor,
    f16* __restrict__ sorted) {
    __shared__ int rk[64];
    int r0 = blockIdx.x * 64;        // grid exactly 1024
    int t = threadIdx.x;
    if (t < 64) {
        int r = r0 + t;
        int s = idx[r];
        rk[t] = offsets[s] + atomicAdd(&cursor[s], 1);
    }
    __syncthreads();
    int lr = t >> 3, li = t & 7;     // 32 rows per pass, 8 lanes x 8 elems each
    #pragma unroll
    for (int k = 0; k < 2; ++k) {
        int r = r0 + k * 32 + lr;
        int rr = rk[k * 32 + lr];
        #pragma unroll 4
        for (int b = 0; b < 16; ++b) {
            const float* src = bonds + ((size_t)b * NB + r) * 64 + li * 8;
            f32x4 v0 = *reinterpret_cast<const f32x4*>(src);
            f32x4 v1 = *reinterpret_cast<const f32x4*>(src + 4);
            f16x8 h = { (f16)v0[0], (f16)v0[1], (f16)v0[2], (f16)v0[3],
                        (f16)v1[0], (f16)v1[1], (f16)v1[2], (f16)v1[3] };
            *reinterpret_cast<f16x8*>(sorted + ((size_t)b * NB + rr) * 64 + li * 8) = h;
        }
    }
}

// ---------------- fused linear-gather + 3-layer MLP ----------------
// block = (batch b, 32-site chunk). 256 threads, 4 waves.
// Gather: 8 lanes per site, each lane owns an exclusive f16x8 elem-chunk; the
// site's rows are CONTIGUOUS in `sorted` (4 KB avg segment) -> pure linear
// stream, no id loads, no shuffles. f32 accumulate, /count, write V f16.
// GEMM1/2: wave w owns cols [64w,64w+64). GEMM3 (N=64): wave w owns [16w,16w+16).
__global__ __launch_bounds__(256, 4) void fused_kernel(
    const f16* __restrict__ sorted, const float* __restrict__ sites, const float* __restrict__ states,
    const int* __restrict__ counts, const int* __restrict__ offsets,
    const float* __restrict__ b1, const float* __restrict__ b2, const float* __restrict__ b3,
    const f16x8* __restrict__ pw1, const f16x8* __restrict__ pw2, const f16x8* __restrict__ pw3,
    float* __restrict__ out) {
    constexpr int STR = 280;                 // f16 row stride: 560B rows, 16B-aligned
    __shared__ f16 bufA[32 * STR];           // V (192 cols), later h2 (256 cols)
    __shared__ f16 bufB[32 * STR];           // h1 (256 cols)
    int t = threadIdx.x;
    int w = t >> 6, lane = t & 63;
    int arow = lane & 15, ag = lane >> 4;
    int blk = blockIdx.x;
    int b = blk >> 6;                        // 64 chunks per batch
    int s0 = (blk & 63) * 32;                // first site of chunk
    int m0 = b * NS + s0;                    // first output row

    // ---- stage sites (cols 64..127) and states (cols 128..191) ----
    {
        #pragma unroll
        for (int p = 0; p < 2; ++p) {
            int i = p * 256 + t;             // 512: 32 rows x 16 chunks
            int row = i >> 4, c4 = i & 15;
            f32x4 v = *reinterpret_cast<const f32x4*>(sites + (size_t)(m0 + row) * 64 + c4 * 4);
            f16x4 h = { (f16)v[0], (f16)v[1], (f16)v[2], (f16)v[3] };
            *reinterpret_cast<f16x4*>(&bufA[row * STR + 64 + c4 * 4]) = h;
        }
        f32x4 v = *reinterpret_cast<const f32x4*>(states + (size_t)b * 64 + (t & 15) * 4);
        f16x4 h = { (f16)v[0], (f16)v[1], (f16)v[2], (f16)v[3] };
        #pragma unroll
        for (int p = 0; p < 2; ++p) {
            int row = p * 16 + (t >> 4), c4 = t & 15;
            *reinterpret_cast<f16x4*>(&bufA[row * STR + 128 + c4 * 4]) = h;
        }
    }

    // ---- gather-mean over sorted bonds (cols 0..63): contiguous segments ----
    {
        int site = t >> 3, li = t & 7;       // 32 sites x 8 lanes
        int s = s0 + site;
        int cnt = counts[s];
        const f16* srow = sorted + ((size_t)b * NB + offsets[s]) * 64 + li * 8;
        float acc[8] = {0.f,0.f,0.f,0.f,0.f,0.f,0.f,0.f};
        int i = 0;
        for (; i + 4 <= cnt; i += 4) {
            f16x8 h0 = *reinterpret_cast<const f16x8*>(srow + (size_t)(i + 0) * 64);
            f16x8 h1 = *reinterpret_cast<const f16x8*>(srow + (size_t)(i + 1) * 64);
            f16x8 h2 = *reinterpret_cast<const f16x8*>(srow + (size_t)(i + 2) * 64);
            f16x8 h3 = *reinterpret_cast<const f16x8*>(srow + (size_t)(i + 3) * 64);
            #pragma unroll
            for (int e = 0; e < 8; ++e)
                acc[e] += (float)h0[e] + (float)h1[e] + (float)h2[e] + (float)h3[e];
        }
        for (; i < cnt; ++i) {
            f16x8 h = *reinterpret_cast<const f16x8*>(srow + (size_t)i * 64);
            #pragma unroll
            for (int e = 0; e < 8; ++e) acc[e] += (float)h[e];
        }
        float inv = 1.0f / (float)(cnt > 1 ? cnt : 1);
        f16x8 o;
        #pragma unroll
        for (int e = 0; e < 8; ++e) o[e] = (f16)(acc[e] * inv);
        *reinterpret_cast<f16x8*>(&bufA[site * STR + li * 8]) = o;
    }
    __syncthreads();

    // ---- GEMM1: h1 = relu(V @ W1 + b1), K=192 ----
    {
        f32x4 acc[2][4];
        #pragma unroll
        for (int ni = 0; ni < 4; ++ni) {
            float bv = b1[w * 64 + ni * 16 + arow];
            acc[0][ni] = f32x4{bv, bv, bv, bv};
            acc[1][ni] = f32x4{bv, bv, bv, bv};
        }
        #pragma unroll
        for (int kt = 0; kt < 6; ++kt) {
            f16x8 af[2], bfr[4];
            #pragma unroll
            for (int mi = 0; mi < 2; ++mi)
                af[mi] = *reinterpret_cast<const f16x8*>(&bufA[(mi * 16 + arow) * STR + kt * 32 + ag * 8]);
            #pragma unroll
            for (int ni = 0; ni < 4; ++ni) bfr[ni] = pw1[(kt * 16 + w * 4 + ni) * 64 + lane];
            #pragma unroll
            for (int mi = 0; mi < 2; ++mi)
                #pragma unroll
                for (int ni = 0; ni < 4; ++ni)
                    acc[mi][ni] = __builtin_amdgcn_mfma_f32_16x16x32_f16(af[mi], bfr[ni], acc[mi][ni], 0, 0, 0);
        }
        #pragma unroll
        for (int mi = 0; mi < 2; ++mi)
            #pragma unroll
            for (int ni = 0; ni < 4; ++ni)
                #pragma unroll
                for (int j = 0; j < 4; ++j) {
                    float x = acc[mi][ni][j]; x = x > 0.f ? x : 0.f;
                    bufB[(mi * 16 + ag * 4 + j) * STR + w * 64 + ni * 16 + arow] = (f16)x;
                }
    }
    __syncthreads();

    // ---- GEMM2: h2 = relu(h1 @ W2 + b2), K=256 ----
    {
        f32x4 acc[2][4];
        #pragma unroll
        for (int ni = 0; ni < 4; ++ni) {
            float bv = b2[w * 64 + ni * 16 + arow];
            acc[0][ni] = f32x4{bv, bv, bv, bv};
            acc[1][ni] = f32x4{bv, bv, bv, bv};
        }
        #pragma unroll
        for (int kt = 0; kt < 8; ++kt) {
            f16x8 af[2], bfr[4];
            #pragma unroll
            for (int mi = 0; mi < 2; ++mi)
                af[mi] = *reinterpret_cast<const f16x8*>(&bufB[(mi * 16 + arow) * STR + kt * 32 + ag * 8]);
            #pragma unroll
            for (int ni = 0; ni < 4; ++ni) bfr[ni] = pw2[(kt * 16 + w * 4 + ni) * 64 + lane];
            #pragma unroll
            for (int mi = 0; mi < 2; ++mi)
                #pragma unroll
                for (int ni = 0; ni < 4; ++ni)
                    acc[mi][ni] = __builtin_amdgcn_mfma_f32_16x16x32_f16(af[mi], bfr[ni], acc[mi][ni], 0, 0, 0);
        }
        __syncthreads();   // all h1 reads done before overwriting bufA
        #pragma unroll
        for (int mi = 0; mi < 2; ++mi)
            #pragma unroll
            for (int ni = 0; ni < 4; ++ni)
                #pragma unroll
                for (int j = 0; j < 4; ++j) {
                    float x = acc[mi][ni][j]; x = x > 0.f ? x : 0.f;
                    bufA[(mi * 16 + ag * 4 + j) * STR + w * 64 + ni * 16 + arow] = (f16)x;
                }
    }
    __syncthreads();

    // ---- GEMM3: out = relu(h2 @ W3 + b3), K=256, N=64 ----
    {
        f32x4 acc[2];
        float bv = b3[w * 16 + arow];
        acc[0] = f32x4{bv, bv, bv, bv};
        acc[1] = f32x4{bv, bv, bv, bv};
        #pragma unroll
        for (int kt = 0; kt < 8; ++kt) {
            f16x8 bfr = pw3[(kt * 4 + w) * 64 + lane];
            #pragma unroll
            for (int mi = 0; mi < 2; ++mi) {
                f16x8 af = *reinterpret_cast<const f16x8*>(&bufA[(mi * 16 + arow) * STR + kt * 32 + ag * 8]);
                acc[mi] = __builtin_amdgcn_mfma_f32_16x16x32_f16(af, bfr, acc[mi], 0, 0, 0);
            }
        }
        #pragma unroll
        for (int mi = 0; mi < 2; ++mi)
            #pragma unroll
            for (int j = 0; j < 4; ++j) {
                float x = acc[mi][j]; x = x > 0.f ? x : 0.f;
                out[(size_t)(m0 + mi * 16 + ag * 4 + j) * 64 + w * 16 + arow] = x;
            }
    }
}

extern "C" void kernel_launch(void* const* d_in, const int* in_sizes, int n_in,
                              void* d_out, int out_size, void* d_ws, size_t ws_size,
                              hipStream_t stream) {
    (void)in_sizes; (void)n_in; (void)out_size; (void)ws_size;
    const float* sites  = (const float*)d_in[0];
    const float* bonds  = (const float*)d_in[1];
    const float* states = (const float*)d_in[2];
    const int*   idx    = (const int*)d_in[3];
    const float* W1 = (const float*)d_in[4];
    const float* b1 = (const float*)d_in[5];
    const float* W2 = (const float*)d_in[6];
    const float* b2 = (const float*)d_in[7];
    const float* W3 = (const float*)d_in[8];
    const float* b3 = (const float*)d_in[9];
    float* out = (float*)d_out;

    char* ws = (char*)d_ws;
    f16* pw1     = (f16*)ws;                      // 96*512 f16
    f16* pw2     = pw1 + 96 * 512;                // 128*512 f16
    f16* pw3     = pw2 + 128 * 512;               // 32*512 f16  (total 262144 B)
    int* counts  = (int*)(ws + 262144);           // 2048 * 4
    int* cursor  = (int*)(ws + 262144 + 8192);    // 2048 * 4
    int* offsets = (int*)(ws + 262144 + 16384);   // 2048 * 4
    f16* sorted  = (f16*)(ws + 262144 + 24576);   // 16*65536*64 f16 = 128 MiB

    hipMemsetAsync(counts, 0, 16384, stream);     // zeros counts + cursor
    pack_count_kernel<<<320, 256, 0, stream>>>(W1, W2, W3, pw1, pw2, pw3, idx, counts);
    scan_kernel<<<1, 64, 0, stream>>>(counts, offsets);
    conv_kernel<<<1024, 256, 0, stream>>>(bonds, idx, offsets, cursor, sorted);
    fused_kernel<<<1024, 256, 0, stream>>>(sorted, sites, states, counts, offsets,
                                           b1, b2, b3,
                                           (const f16x8*)pw1, (const f16x8*)pw2, (const f16x8*)pw3, out);
}

// Round 10
// 83.525 us; speedup vs baseline: 1.6671x; 1.6671x over previous
//
#include <hip/hip_runtime.h>
#include <cstdint>
#include <cstddef>

typedef _Float16 f16;
typedef f16 f16x8 __attribute__((ext_vector_type(8)));
typedef f16 f16x4 __attribute__((ext_vector_type(4)));
typedef float f32x4 __attribute__((ext_vector_type(4)));

constexpr int NS = 2048;     // sites
constexpr int NB = 65536;    // bonds
// d_in order: sites, bonds, states, indices1, W1, b1, W2, b2, W3, b3 (all f32, idx int32)

// ---------------- pack (blocks 0..63) + count (blocks 64..319) ----------------
__global__ void pack_count_kernel(const float* __restrict__ W1, const float* __restrict__ W2,
                                  const float* __restrict__ W3, f16* __restrict__ pw1,
                                  f16* __restrict__ pw2, f16* __restrict__ pw3,
                                  const int* __restrict__ idx, int* __restrict__ counts) {
    if (blockIdx.x < 64) {
        int t = blockIdx.x * 256 + threadIdx.x;   // 16384 threads
        int tt = t >> 6, l = t & 63;
        const float* W; f16* dst; int N, tloc, kt, nt;
        if (tt < 96)       { W = W1; dst = pw1; N = 256; tloc = tt;       kt = tloc >> 4; nt = tloc & 15; }
        else if (tt < 224) { W = W2; dst = pw2; N = 256; tloc = tt - 96;  kt = tloc >> 4; nt = tloc & 15; }
        else               { W = W3; dst = pw3; N = 64;  tloc = tt - 224; kt = tloc >> 2; nt = tloc & 3;  }
        int kbase = kt * 32 + (l >> 4) * 8;
        int n = nt * 16 + (l & 15);
        f16x8 o;
        #pragma unroll
        for (int j = 0; j < 8; ++j) o[j] = (f16)W[(size_t)(kbase + j) * N + n];
        *reinterpret_cast<f16x8*>(&dst[(size_t)(tloc * 64 + l) * 8]) = o;
    } else {
        int i = (blockIdx.x - 64) * 256 + threadIdx.x;   // 65536 threads
        atomicAdd(&counts[idx[i]], 1);
    }
}

__global__ void scan_kernel(const int* __restrict__ counts, int* __restrict__ offsets) {
    int l = threadIdx.x;            // 64 lanes, each owns 32 contiguous sites
    int c[32]; int run = 0;
    #pragma unroll
    for (int i = 0; i < 32; ++i) { c[i] = run; run += counts[l * 32 + i]; }
    int incl = run;
    #pragma unroll
    for (int d = 1; d < 64; d <<= 1) { int v = __shfl_up(incl, d); if (l >= d) incl += v; }
    int excl = incl - run;
    #pragma unroll
    for (int i = 0; i < 32; ++i) offsets[l * 32 + i] = excl + c[i];
}

__global__ void fill_kernel(const int* __restrict__ idx, const int* __restrict__ offsets,
                            int* __restrict__ cursor, int* __restrict__ bucket) {
    int i = blockIdx.x * 256 + threadIdx.x;   // grid exactly 65536
    int s = idx[i];
    int pos = atomicAdd(&cursor[s], 1);
    bucket[offsets[s] + pos] = i;
}

// ---------------- fused gather-pool + 3-layer MLP (slim LDS: 5 blocks/CU) ----------------
// block = (batch b, 32-site chunk). 256 threads, 4 waves.
// bufA = V only (32 x 200 f16, 12.8 KB; dword row-stride 100 -> bank stride 4 -> 2-way = free).
// bufB = h1 then h2 IN PLACE (32 x 280, 17.9 KB). Total 30.7 KB -> 5 blocks/CU.
__global__ __launch_bounds__(256, 5) void fused_kernel(
    const float* __restrict__ bonds, const float* __restrict__ sites, const float* __restrict__ states,
    const int* __restrict__ counts, const int* __restrict__ offsets, const int* __restrict__ bucket,
    const float* __restrict__ b1, const float* __restrict__ b2, const float* __restrict__ b3,
    const f16x8* __restrict__ pw1, const f16x8* __restrict__ pw2, const f16x8* __restrict__ pw3,
    float* __restrict__ out) {
    constexpr int VSTR = 200;                // V row stride (f16): 400B rows
    constexpr int STR  = 280;                // h row stride (f16): 560B rows
    __shared__ f16 bufA[32 * VSTR];          // V (192 cols)
    __shared__ f16 bufB[32 * STR];           // h1, then h2 in place
    int t = threadIdx.x;
    int w = t >> 6, lane = t & 63;
    int arow = lane & 15, ag = lane >> 4;
    int blk = blockIdx.x;
    int b = blk >> 6;                        // 64 chunks per batch
    int s0 = (blk & 63) * 32;                // first site of chunk
    int m0 = b * NS + s0;                    // first output row

    // ---- stage sites (cols 64..127) and states (cols 128..191) ----
    {
        #pragma unroll
        for (int p = 0; p < 2; ++p) {
            int i = p * 256 + t;             // 512: 32 rows x 16 chunks
            int row = i >> 4, c4 = i & 15;
            f32x4 v = *reinterpret_cast<const f32x4*>(sites + (size_t)(m0 + row) * 64 + c4 * 4);
            f16x4 h = { (f16)v[0], (f16)v[1], (f16)v[2], (f16)v[3] };
            *reinterpret_cast<f16x4*>(&bufA[row * VSTR + 64 + c4 * 4]) = h;
        }
        f32x4 v = *reinterpret_cast<const f32x4*>(states + (size_t)b * 64 + (t & 15) * 4);
        f16x4 h = { (f16)v[0], (f16)v[1], (f16)v[2], (f16)v[3] };
        #pragma unroll
        for (int p = 0; p < 2; ++p) {
            int row = p * 16 + (t >> 4), c4 = t & 15;
            *reinterpret_cast<f16x4*>(&bufA[row * VSTR + 128 + c4 * 4]) = h;
        }
    }

    // ---- gather-mean over bonds (cols 0..63), 16-deep pipeline ----
    {
        int slot = t >> 4, f4 = t & 15;      // 16 site-slots x 16 float4-chunks
        const f32x4* base = reinterpret_cast<const f32x4*>(bonds) + (size_t)b * NB * 16;
        #pragma unroll
        for (int sg = 0; sg < 2; ++sg) {
            int srow = sg * 16 + slot;
            int s = s0 + srow;
            int cnt = counts[s];
            const int* q = bucket + offsets[s];
            f32x4 acc = {0.f, 0.f, 0.f, 0.f};
            int i = 0;
            for (; i + 16 <= cnt; i += 16) {
                f32x4 v[16];
                #pragma unroll
                for (int u = 0; u < 16; ++u) v[u] = base[q[i + u] * 16 + f4];
                #pragma unroll
                for (int u = 0; u < 16; ++u) acc += v[u];
            }
            for (; i + 8 <= cnt; i += 8) {
                f32x4 v[8];
                #pragma unroll
                for (int u = 0; u < 8; ++u) v[u] = base[q[i + u] * 16 + f4];
                #pragma unroll
                for (int u = 0; u < 8; ++u) acc += v[u];
            }
            if (i < cnt) {                   // predicated tail: dup loads hit cache
                f32x4 v[8];
                #pragma unroll
                for (int u = 0; u < 8; ++u) {
                    int j = (i + u < cnt) ? (i + u) : i;
                    v[u] = base[q[j] * 16 + f4];
                }
                #pragma unroll
                for (int u = 0; u < 8; ++u) if (i + u < cnt) acc += v[u];
            }
            float inv = 1.0f / (float)(cnt > 1 ? cnt : 1);
            acc *= inv;
            f16x4 h = { (f16)acc[0], (f16)acc[1], (f16)acc[2], (f16)acc[3] };
            *reinterpret_cast<f16x4*>(&bufA[srow * VSTR + f4 * 4]) = h;
        }
    }
    __syncthreads();

    // ---- GEMM1: h1 = relu(V @ W1 + b1), K=192 ----
    {
        f32x4 acc[2][4];
        #pragma unroll
        for (int ni = 0; ni < 4; ++ni) {
            float bv = b1[w * 64 + ni * 16 + arow];
            acc[0][ni] = f32x4{bv, bv, bv, bv};
            acc[1][ni] = f32x4{bv, bv, bv, bv};
        }
        #pragma unroll
        for (int kt = 0; kt < 6; ++kt) {
            f16x8 af[2], bfr[4];
            #pragma unroll
            for (int mi = 0; mi < 2; ++mi)
                af[mi] = *reinterpret_cast<const f16x8*>(&bufA[(mi * 16 + arow) * VSTR + kt * 32 + ag * 8]);
            #pragma unroll
            for (int ni = 0; ni < 4; ++ni) bfr[ni] = pw1[(kt * 16 + w * 4 + ni) * 64 + lane];
            #pragma unroll
            for (int mi = 0; mi < 2; ++mi)
                #pragma unroll
                for (int ni = 0; ni < 4; ++ni)
                    acc[mi][ni] = __builtin_amdgcn_mfma_f32_16x16x32_f16(af[mi], bfr[ni], acc[mi][ni], 0, 0, 0);
        }
        #pragma unroll
        for (int mi = 0; mi < 2; ++mi)
            #pragma unroll
            for (int ni = 0; ni < 4; ++ni)
                #pragma unroll
                for (int j = 0; j < 4; ++j) {
                    float x = acc[mi][ni][j]; x = x > 0.f ? x : 0.f;
                    bufB[(mi * 16 + ag * 4 + j) * STR + w * 64 + ni * 16 + arow] = (f16)x;
                }
    }
    __syncthreads();

    // ---- GEMM2: h2 = relu(h1 @ W2 + b2), K=256; h2 written IN PLACE into bufB ----
    {
        f32x4 acc[2][4];
        #pragma unroll
        for (int ni = 0; ni < 4; ++ni) {
            float bv = b2[w * 64 + ni * 16 + arow];
            acc[0][ni] = f32x4{bv, bv, bv, bv};
            acc[1][ni] = f32x4{bv, bv, bv, bv};
        }
        #pragma unroll
        for (int kt = 0; kt < 8; ++kt) {
            f16x8 af[2], bfr[4];
            #pragma unroll
            for (int mi = 0; mi < 2; ++mi)
                af[mi] = *reinterpret_cast<const f16x8*>(&bufB[(mi * 16 + arow) * STR + kt * 32 + ag * 8]);
            #pragma unroll
            for (int ni = 0; ni < 4; ++ni) bfr[ni] = pw2[(kt * 16 + w * 4 + ni) * 64 + lane];
            #pragma unroll
            for (int mi = 0; mi < 2; ++mi)
                #pragma unroll
                for (int ni = 0; ni < 4; ++ni)
                    acc[mi][ni] = __builtin_amdgcn_mfma_f32_16x16x32_f16(af[mi], bfr[ni], acc[mi][ni], 0, 0, 0);
        }
        __syncthreads();   // ALL h1 reads complete before any h2 write (in-place safety)
        #pragma unroll
        for (int mi = 0; mi < 2; ++mi)
            #pragma unroll
            for (int ni = 0; ni < 4; ++ni)
                #pragma unroll
                for (int j = 0; j < 4; ++j) {
                    float x = acc[mi][ni][j]; x = x > 0.f ? x : 0.f;
                    bufB[(mi * 16 + ag * 4 + j) * STR + w * 64 + ni * 16 + arow] = (f16)x;
                }
    }
    __syncthreads();

    // ---- GEMM3: out = relu(h2 @ W3 + b3), K=256, N=64 ----
    {
        f32x4 acc[2];
        float bv = b3[w * 16 + arow];
        acc[0] = f32x4{bv, bv, bv, bv};
        acc[1] = f32x4{bv, bv, bv, bv};
        #pragma unroll
        for (int kt = 0; kt < 8; ++kt) {
            f16x8 bfr = pw3[(kt * 4 + w) * 64 + lane];
            #pragma unroll
            for (int mi = 0; mi < 2; ++mi) {
                f16x8 af = *reinterpret_cast<const f16x8*>(&bufB[(mi * 16 + arow) * STR + kt * 32 + ag * 8]);
                acc[mi] = __builtin_amdgcn_mfma_f32_16x16x32_f16(af, bfr, acc[mi], 0, 0, 0);
            }
        }
        #pragma unroll
        for (int mi = 0; mi < 2; ++mi)
            #pragma unroll
            for (int j = 0; j < 4; ++j) {
                float x = acc[mi][j]; x = x > 0.f ? x : 0.f;
                out[(size_t)(m0 + mi * 16 + ag * 4 + j) * 64 + w * 16 + arow] = x;
            }
    }
}

extern "C" void kernel_launch(void* const* d_in, const int* in_sizes, int n_in,
                              void* d_out, int out_size, void* d_ws, size_t ws_size,
                              hipStream_t stream) {
    (void)in_sizes; (void)n_in; (void)out_size; (void)ws_size;
    const float* sites  = (const float*)d_in[0];
    const float* bonds  = (const float*)d_in[1];
    const float* states = (const float*)d_in[2];
    const int*   idx    = (const int*)d_in[3];
    const float* W1 = (const float*)d_in[4];
    const float* b1 = (const float*)d_in[5];
    const float* W2 = (const float*)d_in[6];
    const float* b2 = (const float*)d_in[7];
    const float* W3 = (const float*)d_in[8];
    const float* b3 = (const float*)d_in[9];
    float* out = (float*)d_out;

    char* ws = (char*)d_ws;
    f16* pw1     = (f16*)ws;                      // 96*512 f16
    f16* pw2     = pw1 + 96 * 512;                // 128*512 f16
    f16* pw3     = pw2 + 128 * 512;               // 32*512 f16  (total 262144 B)
    int* counts  = (int*)(ws + 262144);           // 2048 * 4
    int* cursor  = (int*)(ws + 262144 + 8192);    // 2048 * 4
    int* offsets = (int*)(ws + 262144 + 16384);   // 2048 * 4
    int* bucket  = (int*)(ws + 262144 + 24576);   // 65536 * 4

    hipMemsetAsync(counts, 0, 16384, stream);     // zeros counts + cursor
    pack_count_kernel<<<320, 256, 0, stream>>>(W1, W2, W3, pw1, pw2, pw3, idx, counts);
    scan_kernel<<<1, 64, 0, stream>>>(counts, offsets);
    fill_kernel<<<256, 256, 0, stream>>>(idx, offsets, cursor, bucket);
    fused_kernel<<<1024, 256, 0, stream>>>(bonds, sites, states, counts, offsets, bucket,
                                           b1, b2, b3,
                                           (const f16x8*)pw1, (const f16x8*)pw2, (const f16x8*)pw3, out);
}